// Round 1
// baseline (599.202 us; speedup 1.0000x reference)
//
#include <hip/hip_runtime.h>
#include <math.h>

namespace {
constexpr int S  = 2048;
constexpr int E  = 1024;
constexpr int NH = 8;
constexpr int DH = 128;
constexpr int TQ = 32;
constexpr int TK = 32;
constexpr float EPSF  = 1e-6f;
constexpr float SCALE = 0.08838834764831845f;  // 1/sqrt(128)
}

// ---------------- kernel 1: gate preactivations ----------------
// one block per timestep t; i_pre[h*S+t], lsf[h*S+t] = log_sigmoid(f_pre)
__global__ __launch_bounds__(256) void gates_kernel(
    const float* __restrict__ q, const float* __restrict__ k, const float* __restrict__ v,
    const float* __restrict__ Wi, const float* __restrict__ bi,
    const float* __restrict__ Wf, const float* __restrict__ bf,
    float* __restrict__ ipre, float* __restrict__ lsf)
{
  const int t = blockIdx.x;
  const int tid = threadIdx.x;
  float ai[8] = {0,0,0,0,0,0,0,0};
  float af[8] = {0,0,0,0,0,0,0,0};
  const float4* Wi4 = reinterpret_cast<const float4*>(Wi);
  const float4* Wf4 = reinterpret_cast<const float4*>(Wf);
  for (int e = tid; e < 3*E; e += 256) {
    float x;
    if (e < E)        x = q[t*E + e];
    else if (e < 2*E) x = k[t*E + (e - E)];
    else              x = v[t*E + (e - 2*E)];
    float4 wi0 = Wi4[2*e], wi1 = Wi4[2*e+1];
    float4 wf0 = Wf4[2*e], wf1 = Wf4[2*e+1];
    ai[0] = fmaf(x, wi0.x, ai[0]); ai[1] = fmaf(x, wi0.y, ai[1]);
    ai[2] = fmaf(x, wi0.z, ai[2]); ai[3] = fmaf(x, wi0.w, ai[3]);
    ai[4] = fmaf(x, wi1.x, ai[4]); ai[5] = fmaf(x, wi1.y, ai[5]);
    ai[6] = fmaf(x, wi1.z, ai[6]); ai[7] = fmaf(x, wi1.w, ai[7]);
    af[0] = fmaf(x, wf0.x, af[0]); af[1] = fmaf(x, wf0.y, af[1]);
    af[2] = fmaf(x, wf0.z, af[2]); af[3] = fmaf(x, wf0.w, af[3]);
    af[4] = fmaf(x, wf1.x, af[4]); af[5] = fmaf(x, wf1.y, af[5]);
    af[6] = fmaf(x, wf1.z, af[6]); af[7] = fmaf(x, wf1.w, af[7]);
  }
  #pragma unroll
  for (int off = 32; off > 0; off >>= 1) {
    #pragma unroll
    for (int hh = 0; hh < 8; hh++) {
      ai[hh] += __shfl_down(ai[hh], off);
      af[hh] += __shfl_down(af[hh], off);
    }
  }
  __shared__ float red[4][16];
  const int wave = tid >> 6, lane = tid & 63;
  if (lane == 0) {
    #pragma unroll
    for (int hh = 0; hh < 8; hh++) { red[wave][hh] = ai[hh]; red[wave][8+hh] = af[hh]; }
  }
  __syncthreads();
  if (tid < 16) {
    float sacc = red[0][tid] + red[1][tid] + red[2][tid] + red[3][tid];
    if (tid < 8) {
      ipre[tid*S + t] = sacc + bi[tid];
    } else {
      int hh = tid - 8;
      float fp = sacc + bf[hh];
      // stable log_sigmoid
      float ls = fminf(fp, 0.f) - log1pf(expf(-fabsf(fp)));
      lsf[hh*S + t] = ls;
    }
  }
}

// ---------------- kernel 2: per-head scans ----------------
// cum = inclusive prefix sum of lsf; a = ipre - cum; m = inclusive prefix max of a;
// dfl = -(cum + m)
__global__ __launch_bounds__(256) void scan_kernel(
    const float* __restrict__ ipre, const float* __restrict__ lsf,
    float* __restrict__ a_out, float* __restrict__ m_out, float* __restrict__ dfl_out)
{
  const int h = blockIdx.x, tid = threadIdx.x;
  constexpr int PER = S / 256;  // 8
  __shared__ float sm[256];
  const int base = h*S + tid*PER;
  float c[PER];
  float run = 0.f;
  #pragma unroll
  for (int u = 0; u < PER; u++) { run += lsf[base+u]; c[u] = run; }
  sm[tid] = run;
  __syncthreads();
  for (int off = 1; off < 256; off <<= 1) {
    float o = (tid >= off) ? sm[tid-off] : 0.f;
    __syncthreads();
    sm[tid] += o;
    __syncthreads();
  }
  float excl = (tid > 0) ? sm[tid-1] : 0.f;
  __syncthreads();
  float av[PER], mloc[PER];
  float lm = -INFINITY;
  #pragma unroll
  for (int u = 0; u < PER; u++) {
    c[u] += excl;                         // inclusive cum
    av[u] = ipre[base+u] - c[u];          // a
    lm = fmaxf(lm, av[u]);
    mloc[u] = lm;
  }
  sm[tid] = lm;
  __syncthreads();
  for (int off = 1; off < 256; off <<= 1) {
    float o = (tid >= off) ? sm[tid-off] : -INFINITY;
    __syncthreads();
    sm[tid] = fmaxf(sm[tid], o);
    __syncthreads();
  }
  float exclm = (tid > 0) ? sm[tid-1] : -INFINITY;
  #pragma unroll
  for (int u = 0; u < PER; u++) {
    float m = fmaxf(exclm, mloc[u]);
    a_out[base+u]  = av[u];
    m_out[base+u]  = m;
    dfl_out[base+u] = -(c[u] + m);
  }
}

// ---------------- kernel 3: causal weighted attention + layernorm ----------------
__global__ __launch_bounds__(256) void attn_kernel(
    const float* __restrict__ q, const float* __restrict__ k, const float* __restrict__ v,
    const float* __restrict__ a_g, const float* __restrict__ m_g, const float* __restrict__ dfl_g,
    const float* __restrict__ ln, float* __restrict__ out)
{
  const int qt  = (int)gridDim.x - 1 - (int)blockIdx.x;  // longest blocks first
  const int h   = blockIdx.y;
  const int tid = threadIdx.x;
  const int qi0 = qt * TQ;

  __shared__ float Qs[TQ][DH+1];   // stride 129: conflict-free strided reads
  __shared__ float Ks[TK][DH+1];
  __shared__ float Vs[TK][DH];     // float4-aligned rows (broadcast reads)
  __shared__ float Cs[TQ][TK+1];
  __shared__ float aj[TK];
  __shared__ float mrow[TQ], dflrow[TQ], srow[TQ];
  __shared__ float mu_s[TQ], rs_s[TQ], inv_s[TQ];

  // stage Q tile
  for (int f = tid; f < TQ*DH/4; f += 256) {
    int row = f >> 5, c4 = f & 31;
    float4 t4 = *reinterpret_cast<const float4*>(q + (size_t)(qi0+row)*E + h*DH + c4*4);
    Qs[row][c4*4+0] = t4.x; Qs[row][c4*4+1] = t4.y;
    Qs[row][c4*4+2] = t4.z; Qs[row][c4*4+3] = t4.w;
  }
  if (tid < TQ) {
    mrow[tid]   = m_g[h*S + qi0 + tid];
    dflrow[tid] = dfl_g[h*S + qi0 + tid];
    srow[tid]   = 0.f;
  }

  float acc0[8] = {0,0,0,0,0,0,0,0};
  float acc1[8] = {0,0,0,0,0,0,0,0};
  const int rg = tid >> 4;       // 0..15 -> rows 2rg, 2rg+1
  const int cg = tid & 15;       // 0..15 -> score cols 2cg,2cg+1 ; PV dims 8cg..8cg+7
  const int r0 = rg*2;
  const int c0 = cg*2;
  const int dbase = cg*8;

  for (int jt = 0; jt <= qt; ++jt) {
    const int j0 = jt * TK;
    __syncthreads();   // protect Ks/Vs/aj from previous iteration readers
    for (int f = tid; f < TK*DH/4; f += 256) {
      int row = f >> 5, c4 = f & 31;
      float4 k4 = *reinterpret_cast<const float4*>(k + (size_t)(j0+row)*E + h*DH + c4*4);
      Ks[row][c4*4+0] = k4.x; Ks[row][c4*4+1] = k4.y;
      Ks[row][c4*4+2] = k4.z; Ks[row][c4*4+3] = k4.w;
      float4 v4 = *reinterpret_cast<const float4*>(v + (size_t)(j0+row)*E + h*DH + c4*4);
      *reinterpret_cast<float4*>(&Vs[row][c4*4]) = v4;
    }
    if (tid < TK) aj[tid] = a_g[h*S + j0 + tid];
    __syncthreads();

    // scores: 2x2 register tile per thread
    float d00=0.f, d01=0.f, d10=0.f, d11=0.f;
    #pragma unroll 8
    for (int kk = 0; kk < DH; ++kk) {
      float q0 = Qs[r0][kk],  q1 = Qs[r0+1][kk];
      float kA = Ks[c0][kk],  kB = Ks[c0+1][kk];
      d00 = fmaf(q0, kA, d00); d01 = fmaf(q0, kB, d01);
      d10 = fmaf(q1, kA, d10); d11 = fmaf(q1, kB, d11);
    }
    {
      const int i0g = qi0 + r0, i1g = i0g + 1;
      const int j0g = j0 + c0,  j1g = j0g + 1;
      const float m0 = mrow[r0], m1 = mrow[r0+1];
      const float a0 = aj[c0],   a1 = aj[c0+1];
      Cs[r0  ][c0  ] = (j0g <= i0g) ? d00*SCALE*__expf(fminf(a0-m0, 0.f)) : 0.f;
      Cs[r0  ][c0+1] = (j1g <= i0g) ? d01*SCALE*__expf(fminf(a1-m0, 0.f)) : 0.f;
      Cs[r0+1][c0  ] = (j0g <= i1g) ? d10*SCALE*__expf(fminf(a0-m1, 0.f)) : 0.f;
      Cs[r0+1][c0+1] = (j1g <= i1g) ? d11*SCALE*__expf(fminf(a1-m1, 0.f)) : 0.f;
    }
    __syncthreads();   // Cs ready

    // row sums for the normalizer
    if (tid < TQ) {
      float ssum = 0.f;
      #pragma unroll
      for (int c = 0; c < TK; ++c) ssum += Cs[tid][c];
      srow[tid] += ssum;
    }

    // PV: 2 rows x 8 dims per thread
    #pragma unroll
    for (int j = 0; j < TK; ++j) {
      float cA = Cs[r0][j], cB = Cs[r0+1][j];
      float4 va = *reinterpret_cast<const float4*>(&Vs[j][dbase]);
      float4 vb = *reinterpret_cast<const float4*>(&Vs[j][dbase+4]);
      acc0[0] = fmaf(cA, va.x, acc0[0]); acc0[1] = fmaf(cA, va.y, acc0[1]);
      acc0[2] = fmaf(cA, va.z, acc0[2]); acc0[3] = fmaf(cA, va.w, acc0[3]);
      acc0[4] = fmaf(cA, vb.x, acc0[4]); acc0[5] = fmaf(cA, vb.y, acc0[5]);
      acc0[6] = fmaf(cA, vb.z, acc0[6]); acc0[7] = fmaf(cA, vb.w, acc0[7]);
      acc1[0] = fmaf(cB, va.x, acc1[0]); acc1[1] = fmaf(cB, va.y, acc1[1]);
      acc1[2] = fmaf(cB, va.z, acc1[2]); acc1[3] = fmaf(cB, va.w, acc1[3]);
      acc1[4] = fmaf(cB, vb.x, acc1[4]); acc1[5] = fmaf(cB, vb.y, acc1[5]);
      acc1[6] = fmaf(cB, vb.z, acc1[6]); acc1[7] = fmaf(cB, vb.w, acc1[7]);
    }
  }

  __syncthreads();
  // park H in Qs (Q no longer needed)
  #pragma unroll
  for (int d = 0; d < 8; ++d) {
    Qs[r0  ][dbase+d] = acc0[d];
    Qs[r0+1][dbase+d] = acc1[d];
  }
  __syncthreads();

  // per-row normalizer + layernorm stats
  if (tid < TQ) {
    const int r = tid;
    float nrm = fmaxf(fabsf(srow[r]), __expf(dflrow[r]));
    float inv = 1.f / (nrm + EPSF);
    float s1 = 0.f;
    for (int d = 0; d < DH; ++d) s1 += Qs[r][d];
    float mu = s1 * inv * (1.f/DH);
    float s2 = 0.f;
    for (int d = 0; d < DH; ++d) {
      float hv = Qs[r][d]*inv - mu;
      s2 = fmaf(hv, hv, s2);
    }
    float rs = rsqrtf(s2*(1.f/DH) + EPSF);
    mu_s[r] = mu; rs_s[r] = rs; inv_s[r] = inv;
  }
  __syncthreads();

  // coalesced output: out[(qi0+row)*E + h*DH + d]
  for (int f = tid; f < TQ*DH; f += 256) {
    int row = f >> 7, d = f & 127;
    float hv = Qs[row][d]*inv_s[row] - mu_s[row];
    out[(size_t)(qi0+row)*E + h*DH + d] = hv * rs_s[row] * ln[h*DH + d];
  }
}

extern "C" void kernel_launch(void* const* d_in, const int* in_sizes, int n_in,
                              void* d_out, int out_size, void* d_ws, size_t ws_size,
                              hipStream_t stream) {
  const float* q  = (const float*)d_in[0];
  const float* k  = (const float*)d_in[1];
  const float* v  = (const float*)d_in[2];
  const float* Wi = (const float*)d_in[3];
  const float* bi = (const float*)d_in[4];
  const float* Wf = (const float*)d_in[5];
  const float* bf = (const float*)d_in[6];
  const float* ln = (const float*)d_in[7];
  float* out = (float*)d_out;

  float* w    = (float*)d_ws;       // 5 * NH*S floats = 320 KB
  float* ipre = w;
  float* lsf  = w + 1*NH*S;
  float* a_g  = w + 2*NH*S;
  float* m_g  = w + 3*NH*S;
  float* dfl  = w + 4*NH*S;

  gates_kernel<<<dim3(S), dim3(256), 0, stream>>>(q, k, v, Wi, bi, Wf, bf, ipre, lsf);
  scan_kernel<<<dim3(NH), dim3(256), 0, stream>>>(ipre, lsf, a_g, m_g, dfl);
  attn_kernel<<<dim3(S/TQ, NH), dim3(256), 0, stream>>>(q, k, v, a_g, m_g, dfl, ln, out);
}

// Round 2
// 162.066 us; speedup vs baseline: 3.6973x; 3.6973x over previous
//
#include <hip/hip_runtime.h>
#include <math.h>

namespace {
constexpr int S  = 2048;
constexpr int E  = 1024;
constexpr int NH = 8;
constexpr int DH = 128;
constexpr float EPSF = 1e-6f;
}

typedef short short8 __attribute__((ext_vector_type(8)));
typedef float f32x16 __attribute__((ext_vector_type(16)));

__device__ __forceinline__ unsigned short f2bf(float x) {
  unsigned int u = __float_as_uint(x);
  unsigned int r = (u + 0x7fffu + ((u >> 16) & 1u)) >> 16;   // RNE, finite inputs
  return (unsigned short)r;
}

// ---------------- kernel 1: gates + bf16 conversion of q,k ----------------
__global__ __launch_bounds__(256) void gates_kernel(
    const float* __restrict__ q, const float* __restrict__ k, const float* __restrict__ v,
    const float* __restrict__ Wi, const float* __restrict__ bi,
    const float* __restrict__ Wf, const float* __restrict__ bf,
    float* __restrict__ ipre, float* __restrict__ lsf,
    unsigned short* __restrict__ qb, unsigned short* __restrict__ kb)
{
  const int t = blockIdx.x;
  const int tid = threadIdx.x;
  float ai[8] = {0,0,0,0,0,0,0,0};
  float af[8] = {0,0,0,0,0,0,0,0};
  const float4* Wi4 = reinterpret_cast<const float4*>(Wi);
  const float4* Wf4 = reinterpret_cast<const float4*>(Wf);
  for (int e = tid; e < 3*E; e += 256) {
    float x;
    if (e < E)        { x = q[t*E + e];        qb[(size_t)t*E + e]       = f2bf(x); }
    else if (e < 2*E) { x = k[t*E + (e - E)];  kb[(size_t)t*E + (e - E)] = f2bf(x); }
    else              { x = v[t*E + (e - 2*E)]; }
    float4 wi0 = Wi4[2*e], wi1 = Wi4[2*e+1];
    float4 wf0 = Wf4[2*e], wf1 = Wf4[2*e+1];
    ai[0] = fmaf(x, wi0.x, ai[0]); ai[1] = fmaf(x, wi0.y, ai[1]);
    ai[2] = fmaf(x, wi0.z, ai[2]); ai[3] = fmaf(x, wi0.w, ai[3]);
    ai[4] = fmaf(x, wi1.x, ai[4]); ai[5] = fmaf(x, wi1.y, ai[5]);
    ai[6] = fmaf(x, wi1.z, ai[6]); ai[7] = fmaf(x, wi1.w, ai[7]);
    af[0] = fmaf(x, wf0.x, af[0]); af[1] = fmaf(x, wf0.y, af[1]);
    af[2] = fmaf(x, wf0.z, af[2]); af[3] = fmaf(x, wf0.w, af[3]);
    af[4] = fmaf(x, wf1.x, af[4]); af[5] = fmaf(x, wf1.y, af[5]);
    af[6] = fmaf(x, wf1.z, af[6]); af[7] = fmaf(x, wf1.w, af[7]);
  }
  #pragma unroll
  for (int off = 32; off > 0; off >>= 1) {
    #pragma unroll
    for (int hh = 0; hh < 8; hh++) {
      ai[hh] += __shfl_down(ai[hh], off);
      af[hh] += __shfl_down(af[hh], off);
    }
  }
  __shared__ float red[4][16];
  const int wave = tid >> 6, lane = tid & 63;
  if (lane == 0) {
    #pragma unroll
    for (int hh = 0; hh < 8; hh++) { red[wave][hh] = ai[hh]; red[wave][8+hh] = af[hh]; }
  }
  __syncthreads();
  if (tid < 16) {
    float sacc = red[0][tid] + red[1][tid] + red[2][tid] + red[3][tid];
    if (tid < 8) {
      ipre[tid*S + t] = sacc + bi[tid];
    } else {
      int hh = tid - 8;
      float fp = sacc + bf[hh];
      float ls = fminf(fp, 0.f) - log1pf(expf(-fabsf(fp)));
      lsf[hh*S + t] = ls;
    }
  }
}

// ---------------- kernel 2: V transpose to bf16, Vt[h][d][j] ----------------
__global__ __launch_bounds__(256) void vtrans_kernel(
    const float* __restrict__ v, unsigned short* __restrict__ vt)
{
  __shared__ float Ts[64][65];
  const int j0 = blockIdx.x * 64, d0 = blockIdx.y * 64, h = blockIdx.z;
  const int c = threadIdx.x & 63, r4 = threadIdx.x >> 6;
  #pragma unroll
  for (int rr = 0; rr < 16; ++rr) {
    int r = r4*16 + rr;
    Ts[r][c] = v[(size_t)(j0 + r)*E + h*DH + d0 + c];
  }
  __syncthreads();
  #pragma unroll
  for (int rr = 0; rr < 16; ++rr) {
    int r = r4*16 + rr;
    vt[(size_t)(h*DH + d0 + r)*S + j0 + c] = f2bf(Ts[c][r]);
  }
}

// ---------------- kernel 3: per-head scans -> a, m ----------------
__global__ __launch_bounds__(256) void scan_kernel(
    const float* __restrict__ ipre, const float* __restrict__ lsf,
    float* __restrict__ a_out, float* __restrict__ m_out)
{
  const int h = blockIdx.x, tid = threadIdx.x;
  constexpr int PER = S / 256;  // 8
  __shared__ float sm[256];
  const int base = h*S + tid*PER;
  float c[PER];
  float run = 0.f;
  #pragma unroll
  for (int u = 0; u < PER; u++) { run += lsf[base+u]; c[u] = run; }
  sm[tid] = run;
  __syncthreads();
  for (int off = 1; off < 256; off <<= 1) {
    float o = (tid >= off) ? sm[tid-off] : 0.f;
    __syncthreads();
    sm[tid] += o;
    __syncthreads();
  }
  float excl = (tid > 0) ? sm[tid-1] : 0.f;
  __syncthreads();
  float av[PER], mloc[PER];
  float lm = -INFINITY;
  #pragma unroll
  for (int u = 0; u < PER; u++) {
    c[u] += excl;
    av[u] = ipre[base+u] - c[u];
    lm = fmaxf(lm, av[u]);
    mloc[u] = lm;
  }
  sm[tid] = lm;
  __syncthreads();
  for (int off = 1; off < 256; off <<= 1) {
    float o = (tid >= off) ? sm[tid-off] : -INFINITY;
    __syncthreads();
    sm[tid] = fmaxf(sm[tid], o);
    __syncthreads();
  }
  float exclm = (tid > 0) ? sm[tid-1] : -INFINITY;
  #pragma unroll
  for (int u = 0; u < PER; u++) {
    float m = fmaxf(exclm, mloc[u]);
    a_out[base+u] = av[u];
    m_out[base+u] = m;
  }
}

// ---------------- kernel 4: MFMA causal decay-attention + LN ----------------
// block b: head = b&7, pair p = b>>3 -> Q-tiles p and 63-p (each block = 17 K-iters)
__global__ __launch_bounds__(256) void attn_kernel(
    const unsigned short* __restrict__ qb, const unsigned short* __restrict__ kb,
    const unsigned short* __restrict__ vt,
    const float* __restrict__ a_g, const float* __restrict__ m_g,
    const float* __restrict__ ln, float* __restrict__ out)
{
  const int p    = blockIdx.x >> 3;
  const int h    = blockIdx.x & 7;
  const int tid  = threadIdx.x;
  const int w    = tid >> 6;        // wave 0..3 -> score cols / O dims 32w..32w+31
  const int lane = tid & 63;
  const int l31  = lane & 31;
  const int half = lane >> 5;

  __shared__ float ajs[128];
  __shared__ float mrow[32];
  __shared__ short Ps[32][136];     // P tile, A-layout source (pad 136 bf16)
  __shared__ float Hs[32][132];     // O tile for LN

  for (int phase = 0; phase < 2; ++phase) {
    const int qt  = (phase == 0) ? p : 63 - p;
    const int qi0 = qt * 32;
    const int niter = (qt + 4) >> 2;          // ceil((qt+1)*32 / 128)

    __syncthreads();                          // protect mrow/Hs across phases
    if (tid < 32) mrow[tid] = m_g[h*S + qi0 + tid];

    // Q fragments (A operand, 32x32x16): m=l31, k=16s+8*half+j, held in regs all phase
    short8 qf[8];
    #pragma unroll
    for (int s = 0; s < 8; ++s)
      qf[s] = *reinterpret_cast<const short8*>(
          qb + (size_t)(qi0 + l31)*E + h*DH + 16*s + 8*half);

    f32x16 acc = {0,0,0,0,0,0,0,0,0,0,0,0,0,0,0,0};
    __syncthreads();                          // mrow visible
    float mreg[16];
    #pragma unroll
    for (int r = 0; r < 16; ++r) mreg[r] = mrow[(r&3) + 8*(r>>2) + 4*half];

    for (int jt = 0; jt < niter; ++jt) {
      const int j0 = jt * 128;
      __syncthreads();                        // prev iter's Ps/ajs consumers done
      if (tid < 128) ajs[tid] = a_g[h*S + j0 + tid];

      // QK^T: B operand = K rows direct from global (d contiguous per lane)
      f32x16 qk = {0,0,0,0,0,0,0,0,0,0,0,0,0,0,0,0};
      #pragma unroll
      for (int s = 0; s < 8; ++s) {
        short8 kf = *reinterpret_cast<const short8*>(
            kb + (size_t)(j0 + 32*w + l31)*E + h*DH + 16*s + 8*half);
        qk = __builtin_amdgcn_mfma_f32_32x32x16_bf16(qf[s], kf, qk, 0, 0, 0);
      }
      __syncthreads();                        // ajs staged; Ps writable

      // P = mask(j<=i) * qk * exp(a_j - m_i)   (normalizer & 1/sqrt(DH) cancel in LN)
      const int   jcol = j0 + 32*w + l31;
      const float ajv  = ajs[32*w + l31];
      #pragma unroll
      for (int r = 0; r < 16; ++r) {
        const int iloc = (r&3) + 8*(r>>2) + 4*half;
        const int ig   = qi0 + iloc;
        float pv = (jcol <= ig) ? qk[r] * __expf(ajv - mreg[r]) : 0.f;
        Ps[iloc][32*w + l31] = (short)f2bf(pv);
      }
      __syncthreads();                        // Ps ready

      // P @ V: A = P from LDS (j contiguous), B = Vt direct from global (j contiguous)
      #pragma unroll
      for (int s = 0; s < 8; ++s) {
        short8 pf = *reinterpret_cast<const short8*>(&Ps[l31][16*s + 8*half]);
        short8 vf = *reinterpret_cast<const short8*>(
            vt + (size_t)(h*DH + 32*w + l31)*S + j0 + 16*s + 8*half);
        acc = __builtin_amdgcn_mfma_f32_32x32x16_bf16(pf, vf, acc, 0, 0, 0);
      }
    }

    // epilogue: LN over DH (normalizer cancels: per-row positive scale)
    __syncthreads();
    #pragma unroll
    for (int r = 0; r < 16; ++r)
      Hs[(r&3) + 8*(r>>2) + 4*half][32*w + l31] = acc[r];
    __syncthreads();
    {
      const int row = tid >> 3, seg = tid & 7;
      float vals[16];
      #pragma unroll
      for (int c4 = 0; c4 < 4; ++c4) {
        float4 v4 = *reinterpret_cast<const float4*>(&Hs[row][seg*16 + c4*4]);
        vals[c4*4+0]=v4.x; vals[c4*4+1]=v4.y; vals[c4*4+2]=v4.z; vals[c4*4+3]=v4.w;
      }
      float s1 = 0.f, s2 = 0.f;
      #pragma unroll
      for (int c = 0; c < 16; ++c) { s1 += vals[c]; s2 = fmaf(vals[c], vals[c], s2); }
      #pragma unroll
      for (int off = 1; off < 8; off <<= 1) {
        s1 += __shfl_xor(s1, off);
        s2 += __shfl_xor(s2, off);
      }
      const float mu  = s1 * (1.f/128.f);
      float var = fmaxf(s2 * (1.f/128.f) - mu*mu, 0.f);
      const float rs  = rsqrtf(var + EPSF);
      const size_t ob = (size_t)(qi0 + row)*E + h*DH + seg*16;
      #pragma unroll
      for (int c = 0; c < 16; ++c)
        out[ob + c] = (vals[c] - mu) * rs * ln[h*DH + seg*16 + c];
    }
  }
}

extern "C" void kernel_launch(void* const* d_in, const int* in_sizes, int n_in,
                              void* d_out, int out_size, void* d_ws, size_t ws_size,
                              hipStream_t stream) {
  const float* q  = (const float*)d_in[0];
  const float* k  = (const float*)d_in[1];
  const float* v  = (const float*)d_in[2];
  const float* Wi = (const float*)d_in[3];
  const float* bi = (const float*)d_in[4];
  const float* Wf = (const float*)d_in[5];
  const float* bf = (const float*)d_in[6];
  const float* ln = (const float*)d_in[7];
  float* out = (float*)d_out;

  // workspace carve-up: 3 x 4MB bf16 + 4 x 64KB f32 = 12.5 MB
  char* base = (char*)d_ws;
  unsigned short* qb = (unsigned short*)(base);
  unsigned short* kb = (unsigned short*)(base + (size_t)S*E*2);
  unsigned short* vt = (unsigned short*)(base + (size_t)S*E*4);
  float* fbase = (float*)(base + (size_t)S*E*6);
  float* ipre = fbase;
  float* lsf  = fbase + 1*NH*S;
  float* a_g  = fbase + 2*NH*S;
  float* m_g  = fbase + 3*NH*S;

  gates_kernel<<<dim3(S), dim3(256), 0, stream>>>(q, k, v, Wi, bi, Wf, bf, ipre, lsf, qb, kb);
  vtrans_kernel<<<dim3(S/64, DH/64, NH), dim3(256), 0, stream>>>(v, vt);
  scan_kernel<<<dim3(NH), dim3(256), 0, stream>>>(ipre, lsf, a_g, m_g);
  attn_kernel<<<dim3(256), dim3(256), 0, stream>>>(qb, kb, vt, a_g, m_g, ln, out);
}